// Round 17
// baseline (154.156 us; speedup 1.0000x reference)
//
#include <hip/hip_runtime.h>
#include <hip/hip_bf16.h>

#define B_ 4
#define S_ 4096
#define E_ 1024
#define D_ 128

typedef unsigned short u16;
typedef __bf16 bf16x8 __attribute__((ext_vector_type(8)));
typedef unsigned short u16x8 __attribute__((ext_vector_type(8)));
typedef float f32x4 __attribute__((ext_vector_type(4)));

__device__ inline u16 f2bf(float f) {
    __bf16 h = (__bf16)f;
    return __builtin_bit_cast(u16, h);
}

// direct global->LDS DMA, 16B per lane, no VGPR round-trip
__device__ inline void gload16(const void* g, void* l) {
    __builtin_amdgcn_global_load_lds(
        (const __attribute__((address_space(1))) void*)g,
        (__attribute__((address_space(3))) void*)l, 16, 0, 0);
}

__device__ inline bf16x8 cvt8(float4 lo, float4 hi) {
    union { bf16x8 v; __bf16 e[8]; } a;
    a.e[0] = (__bf16)lo.x; a.e[1] = (__bf16)lo.y;
    a.e[2] = (__bf16)lo.z; a.e[3] = (__bf16)lo.w;
    a.e[4] = (__bf16)hi.x; a.e[5] = (__bf16)hi.y;
    a.e[6] = (__bf16)hi.z; a.e[7] = (__bf16)hi.w;
    return a.v;
}

// VALU-pipe (DPP) butterfly reductions over 16-lane rows.
__device__ inline float dpp_max16(float x) {
    int v = __builtin_bit_cast(int, x);
    x = fmaxf(x, __builtin_bit_cast(float, __builtin_amdgcn_update_dpp(0, v, 0xB1, 0xF, 0xF, true)));
    v = __builtin_bit_cast(int, x);
    x = fmaxf(x, __builtin_bit_cast(float, __builtin_amdgcn_update_dpp(0, v, 0x4E, 0xF, 0xF, true)));
    v = __builtin_bit_cast(int, x);
    x = fmaxf(x, __builtin_bit_cast(float, __builtin_amdgcn_update_dpp(0, v, 0x141, 0xF, 0xF, true)));
    v = __builtin_bit_cast(int, x);
    x = fmaxf(x, __builtin_bit_cast(float, __builtin_amdgcn_update_dpp(0, v, 0x140, 0xF, 0xF, true)));
    return x;
}
__device__ inline float dpp_add16(float x) {
    int v = __builtin_bit_cast(int, x);
    x += __builtin_bit_cast(float, __builtin_amdgcn_update_dpp(0, v, 0xB1, 0xF, 0xF, true));
    v = __builtin_bit_cast(int, x);
    x += __builtin_bit_cast(float, __builtin_amdgcn_update_dpp(0, v, 0x4E, 0xF, 0xF, true));
    v = __builtin_bit_cast(int, x);
    x += __builtin_bit_cast(float, __builtin_amdgcn_update_dpp(0, v, 0x141, 0xF, 0xF, true));
    v = __builtin_bit_cast(int, x);
    x += __builtin_bit_cast(float, __builtin_amdgcn_update_dpp(0, v, 0x140, 0xF, 0xF, true));
    return x;
}

// ---------------------------------------------------------------------------
// Kernel 0: W [E,D] f32 -> Wt2, the exact per-K-step LDS image (r16).
// ---------------------------------------------------------------------------
__global__ __launch_bounds__(256) void wt_kernel(const float* __restrict__ Wq,
                                                 const float* __restrict__ Wk,
                                                 const float* __restrict__ Wv,
                                                 u16* __restrict__ Wt) {
    int sid = blockIdx.x * 256 + threadIdx.x;   // 0 .. 49151 (16B slots)
    int l = sid & 63;
    int t8 = (sid >> 6) & 7;
    int ks = (sid >> 9) & 31;
    int w = sid >> 14;
    int g = l >> 4;
    int c = l & 15;
    int d = t8 * 16 + c;
    const float* W = (w == 0) ? Wq : ((w == 1) ? Wk : Wv);
    union { u16x8 v; u16 e[8]; } pk;
#pragma unroll
    for (int jj = 0; jj < 8; jj++) {
        int e = ks * 32 + g * 8 + jj;
        float v = W[(size_t)e * D_ + d];
        if (w == 0) v *= 0.08838834764831845f;   // 1/sqrt(128)
        pk.e[jj] = f2bf(v);
    }
    *(u16x8*)((char*)Wt + (size_t)sid * 16) = pk.v;
}

// ---------------------------------------------------------------------------
// Kernel 1: QKV LDS-staged GEMM, counted-vmcnt schedule (unchanged r16).
// ---------------------------------------------------------------------------
__global__ __launch_bounds__(512, 2) void qkv_fused(const float* __restrict__ x,
                                                    const u16* __restrict__ Wt,
                                                    u16* __restrict__ q,
                                                    u16* __restrict__ k,
                                                    u16* __restrict__ vT) {
    const int mrow0 = blockIdx.x * 64;
    const int wv = threadIdx.x >> 6;   // 0..7
    const int l = threadIdx.x & 63;
    const int g = l >> 4;
    const int c = l & 15;
    const int wr = wv >> 2;            // 0..1 (32-row half)
    const int wc = wv & 3;             // 0..3 (96-col group)

    __shared__ __align__(16) char wlds[2][24 * 1024];   // 48 KB dbuf W-tile

    auto STAGE_W = [&](int buf, int ksIdx) {
#pragma unroll
        for (int ii = 0; ii < 3; ii++) {
            int ct = wv * 3 + ii;                  // 0..23 ; w=ct>>3, t8=ct&7
            const char* gp = (const char*)Wt
                + ((size_t)(((ct >> 3) * 32 + ksIdx) * 8 + (ct & 7)) * 1024) + l * 16;
            gload16(gp, wlds[buf] + ct * 1024);
        }
    };

    const float* xrow[2];
#pragma unroll
    for (int sub = 0; sub < 2; sub++)
        xrow[sub] = x + (size_t)(mrow0 + wr * 32 + sub * 16 + c) * E_ + g * 8;

    f32x4 acc[2][6] = {};

    auto MF = [&](int buf, bf16x8 av0, bf16x8 av1) {
#pragma unroll
        for (int ct = 0; ct < 6; ct++) {
            u16x8 braw = *(const u16x8*)(wlds[buf] + (wc * 6 + ct) * 1024 + l * 16);
            bf16x8 bw = __builtin_bit_cast(bf16x8, braw);
            acc[0][ct] = __builtin_amdgcn_mfma_f32_16x16x32_bf16(av0, bw, acc[0][ct], 0, 0, 0);
            acc[1][ct] = __builtin_amdgcn_mfma_f32_16x16x32_bf16(av1, bw, acc[1][ct], 0, 0, 0);
        }
    };

    STAGE_W(0, 0);
    __builtin_amdgcn_sched_barrier(0);
    float4 xa00 = *(const float4*)(xrow[0]);
    float4 xa01 = *(const float4*)(xrow[0] + 4);
    float4 xa10 = *(const float4*)(xrow[1]);
    float4 xa11 = *(const float4*)(xrow[1] + 4);
    float4 xb00 = *(const float4*)(xrow[0] + 32);
    float4 xb01 = *(const float4*)(xrow[0] + 36);
    float4 xb10 = *(const float4*)(xrow[1] + 32);
    float4 xb11 = *(const float4*)(xrow[1] + 36);
    asm volatile("s_waitcnt vmcnt(8)" ::: "memory");
    __builtin_amdgcn_s_barrier();

    int buf = 0;
    for (int it = 0; it < 16; it++) {
        STAGE_W(buf ^ 1, 2 * it + 1);
        __builtin_amdgcn_sched_barrier(0);
        {
            bf16x8 av0 = cvt8(xa00, xa01);
            bf16x8 av1 = cvt8(xa10, xa11);
            if (it < 15) {
                xa00 = *(const float4*)(xrow[0] + (2 * it + 2) * 32);
                xa01 = *(const float4*)(xrow[0] + (2 * it + 2) * 32 + 4);
                xa10 = *(const float4*)(xrow[1] + (2 * it + 2) * 32);
                xa11 = *(const float4*)(xrow[1] + (2 * it + 2) * 32 + 4);
            }
            MF(buf, av0, av1);
        }
        if (it < 15) asm volatile("s_waitcnt vmcnt(4) lgkmcnt(0)" ::: "memory");
        else         asm volatile("s_waitcnt vmcnt(0) lgkmcnt(0)" ::: "memory");
        __builtin_amdgcn_s_barrier();
        buf ^= 1;

        if (it < 15) STAGE_W(buf ^ 1, 2 * it + 2);
        __builtin_amdgcn_sched_barrier(0);
        {
            bf16x8 av0 = cvt8(xb00, xb01);
            bf16x8 av1 = cvt8(xb10, xb11);
            if (it < 15) {
                xb00 = *(const float4*)(xrow[0] + (2 * it + 3) * 32);
                xb01 = *(const float4*)(xrow[0] + (2 * it + 3) * 32 + 4);
                xb10 = *(const float4*)(xrow[1] + (2 * it + 3) * 32);
                xb11 = *(const float4*)(xrow[1] + (2 * it + 3) * 32 + 4);
            }
            MF(buf, av0, av1);
        }
        if (it < 15) {
            asm volatile("s_waitcnt vmcnt(4) lgkmcnt(0)" ::: "memory");
            __builtin_amdgcn_s_barrier();
            buf ^= 1;
        }
    }

#pragma unroll
    for (int sub = 0; sub < 2; sub++) {
#pragma unroll
        for (int ct = 0; ct < 6; ct++) {
            int gc = (wc * 6 + ct) * 16;
            int proj = gc >> 7;
            int dcol = gc & 127;
            if (proj < 2) {
                u16* dst = proj ? k : q;
#pragma unroll
                for (int j = 0; j < 4; j++) {
                    int row = mrow0 + wr * 32 + sub * 16 + g * 4 + j;
                    dst[(size_t)row * D_ + dcol + c] = f2bf(acc[sub][ct][j]);
                }
            } else {
                int srow = mrow0 + wr * 32 + sub * 16 + g * 4;
                int b = srow >> 12;
                int s = srow & 4095;
                ushort4 pk;
                pk.x = f2bf(acc[sub][ct][0]);
                pk.y = f2bf(acc[sub][ct][1]);
                pk.z = f2bf(acc[sub][ct][2]);
                pk.w = f2bf(acc[sub][ct][3]);
                *(ushort4*)(vT + ((size_t)(b * D_ + dcol + c)) * S_ + s) = pk;
            }
        }
    }
}

// ---------------------------------------------------------------------------
// Kernel 2: flash attention, 32 q-rows per wave (LDS-read amortization).
// r16 diagnosis: LDS pipe ~71% occupied per round (8 waves x 34 b128 reads
// for only 16 q-rows each). Now each wave owns 32 q-rows (2 Q-frag sets,
// o[2][8]) so K/V/P reads amortize over 2x work: 18 b128/wave/round.
// Block: 512 thr = 2 q-halves x 4 KV-groups; KVBLK=32; dbuf per group
// (4 grp x 2 x 16KB = 128KB); ONE barrier per round, 32 rounds (r11's
// regression was single-buffer + 64 barriers + 16-row waves).
// K: r14's [32][256B] row-XOR staging. V: [128 d][64B] rows, (d&3) XOR
// swizzle realized on the global source (linear gload_lds dest).
// 4-way (m,l,o) merge epilogue through LDS overlay.
// ---------------------------------------------------------------------------
__global__ __launch_bounds__(512, 2) void attn_kernel(const u16* __restrict__ q,
                                                      const u16* __restrict__ k,
                                                      const u16* __restrict__ vT,
                                                      float* __restrict__ out) {
    // bijective XCD-chunk swizzle (nwg=256, 8 XCDs, chunk=32)
    int bid = blockIdx.x;
    int sw = (bid & 7) * 32 + (bid >> 3);
    const int b = sw >> 6;          // batch 0..3 (2 XCDs per batch)
    const int qt = sw & 63;         // q-tile 0..63 (64 rows)
    const int wv = threadIdx.x >> 6;    // 0..7
    const int wq = wv >> 2;             // q-half (32 rows)
    const int grp = wv & 3;             // kv group: tiles t*4+grp
    const int l = threadIdx.x & 63;
    const int g = l >> 4;
    const int c = l & 15;

    __shared__ __align__(16) char kv_lds[4 * 32768];   // [grp][buf][K 8K | V 8K]
    __shared__ __align__(16) u16 plds[8][1024];        // per-wave [32][32] bf16
    __shared__ float cmB[4][64], clB[4][64];
    u16* pw = &plds[wv][0];
    char* gbase = kv_lds + grp * 32768;

    const char* kbb = (const char*)(k + (size_t)b * S_ * D_);
    const char* vbb = (const char*)(vT + (size_t)b * D_ * S_);

    // Q fragments: 2 subs x 4 ks
    bf16x8 aq[2][4];
#pragma unroll
    for (int sub = 0; sub < 2; sub++) {
        const u16* qp = q + ((size_t)(b * S_ + qt * 64 + wq * 32 + sub * 16 + c)) * D_ + g * 8;
#pragma unroll
        for (int ks = 0; ks < 4; ks++) aq[sub][ks] = *(const bf16x8*)(qp + ks * 32);
    }

    f32x4 o[2][8] = {};
    float m[2][4], ll[2][4];
#pragma unroll
    for (int sub = 0; sub < 2; sub++)
#pragma unroll
        for (int j = 0; j < 4; j++) { m[sub][j] = -1e30f; ll[sub][j] = 0.0f; }

    // stage one 32-kv tile (K [32][256B] + V [128][64B]); 8 instrs per wave
    auto STAGE = [&](int buf, int kvbase) {
        char* dst = gbase + buf * 16384;
#pragma unroll
        for (int ii = 0; ii < 4; ii++) {           // K rows
            int i = wq * 4 + ii;                   // 0..7, 1KB each
            int row = i * 4 + (l >> 4);
            int colb = (l & 15) * 16;
            const char* gp = kbb + (size_t)(kvbase + row) * 256 + (colb ^ ((row & 7) << 4));
            gload16(gp, dst + i * 1024);
        }
#pragma unroll
        for (int ii = 0; ii < 4; ii++) {           // V d-rows (64B each)
            int i = wq * 4 + ii;
            int d = i * 16 + (l >> 2);
            int colb = (l & 3) * 16;
            const char* gp = vbb + (size_t)d * 8192 + (size_t)kvbase * 2
                           + (colb ^ (((l >> 2) & 3) << 4));
            gload16(gp, dst + 8192 + i * 1024);
        }
    };

    STAGE(0, grp * 32);
    __syncthreads();                 // drains vmcnt: buf0 ready
    const int swzK = (c & 7) << 4;
    const int swzP = (c & 3) << 4;

    int buf = 0;
    for (int t = 0; t < 32; t++) {
        if (t < 31) STAGE(buf ^ 1, ((t + 1) * 4 + grp) * 32);

        const char* kbuf = gbase + buf * 16384;
        const char* vbuf = kbuf + 8192;

        // ---- S = Q K^T : 2 kv-subtiles x K-dim 128; K-frags shared by subs ----
        f32x4 s[2][2] = {};
        __builtin_amdgcn_s_setprio(1);
#pragma unroll
        for (int tt = 0; tt < 2; tt++) {
            int rb = (tt * 16 + c) * 256;
#pragma unroll
            for (int ks = 0; ks < 4; ks++) {
                u16x8 kr = *(const u16x8*)(kbuf + rb + ((ks * 64 + g * 16) ^ swzK));
                bf16x8 bk = __builtin_bit_cast(bf16x8, kr);
                s[0][tt] = __builtin_amdgcn_mfma_f32_16x16x32_bf16(aq[0][ks], bk, s[0][tt], 0, 0, 0);
                s[1][tt] = __builtin_amdgcn_mfma_f32_16x16x32_bf16(aq[1][ks], bk, s[1][tt], 0, 0, 0);
            }
        }
        __builtin_amdgcn_s_setprio(0);

        // ---- online softmax: DPP reduce + defer-max (THR=8) ----
        float tmj[2][4];
        bool need = false;
#pragma unroll
        for (int sub = 0; sub < 2; sub++)
#pragma unroll
            for (int j = 0; j < 4; j++) {
                float tm = fmaxf(s[sub][0][j], s[sub][1][j]);
                tm = dpp_max16(tm);
                tmj[sub][j] = tm;
                need = need || (tm > m[sub][j] + 8.0f);
            }
        if (__any(need)) {
#pragma unroll
            for (int sub = 0; sub < 2; sub++)
#pragma unroll
                for (int j = 0; j < 4; j++) {
                    float mn = fmaxf(m[sub][j], tmj[sub][j]);
                    float alpha = exp2f((m[sub][j] - mn) * 1.44269504f);
                    ll[sub][j] *= alpha;
#pragma unroll
                    for (int ct = 0; ct < 8; ct++) o[sub][ct][j] *= alpha;
                    m[sub][j] = mn;
                }
        }
        float pv[2][2][4];
#pragma unroll
        for (int sub = 0; sub < 2; sub++)
#pragma unroll
            for (int j = 0; j < 4; j++) {
                float rs = 0.f;
#pragma unroll
                for (int tt = 0; tt < 2; tt++) {
                    float p = exp2f((s[sub][tt][j] - m[sub][j]) * 1.44269504f);
                    pv[sub][tt][j] = p;
                    rs += p;
                }
                ll[sub][j] += dpp_add16(rs);
            }

        // ---- P -> LDS (wave-private [32 q][32 kv], (row&3) XOR) ----
#pragma unroll
        for (int sub = 0; sub < 2; sub++)
#pragma unroll
            for (int tt = 0; tt < 2; tt++)
#pragma unroll
                for (int j = 0; j < 4; j++) {
                    int row = sub * 16 + g * 4 + j;
                    int col = tt * 16 + c;
                    int byte = row * 64 + ((col * 2) ^ ((row & 3) << 4));
                    *(u16*)((char*)pw + byte) = f2bf(pv[sub][tt][j]);
                }

        // ---- PV: O[sub] += P[sub][16,32] * V[32,128] ----
        bf16x8 pa[2];
#pragma unroll
        for (int sub = 0; sub < 2; sub++) {
            int pbyte = (sub * 16 + c) * 64 + ((g * 16) ^ swzP);
            pa[sub] = __builtin_bit_cast(bf16x8, *(const u16x8*)((char*)pw + pbyte));
        }
        __builtin_amdgcn_s_setprio(1);
#pragma unroll
        for (int ct = 0; ct < 8; ct++) {
            int vbyte = (ct * 16 + c) * 64 + ((g * 16) ^ swzP);   // (d&3)==(c&3)
            bf16x8 bv = __builtin_bit_cast(bf16x8, *(const u16x8*)(vbuf + vbyte));
            o[0][ct] = __builtin_amdgcn_mfma_f32_16x16x32_bf16(pa[0], bv, o[0][ct], 0, 0, 0);
            o[1][ct] = __builtin_amdgcn_mfma_f32_16x16x32_bf16(pa[1], bv, o[1][ct], 0, 0, 0);
        }
        __builtin_amdgcn_s_setprio(0);

        __syncthreads();    // drain staging vmcnt + round barrier
        buf ^= 1;
    }

    // ---- 4-way merge: grps 1..3 -> LDS overlay, grp 0 merges and stores ----
    float* co = (float*)kv_lds;     // 96KB overlay, staging complete
    if (grp != 0) {
        float* cg = co + (size_t)(grp - 1) * (64 * 128);
#pragma unroll
        for (int sub = 0; sub < 2; sub++) {
#pragma unroll
            for (int ct = 0; ct < 8; ct++)
#pragma unroll
                for (int j = 0; j < 4; j++) {
                    int r = wq * 32 + sub * 16 + g * 4 + j;
                    cg[(size_t)r * 128 + ct * 16 + c] = o[sub][ct][j];
                }
            if (c == 0) {
#pragma unroll
                for (int j = 0; j < 4; j++) {
                    int r = wq * 32 + sub * 16 + g * 4 + j;
                    cmB[grp][r] = m[sub][j];
                    clB[grp][r] = ll[sub][j];
                }
            }
        }
    }
    __syncthreads();
    if (grp == 0) {
#pragma unroll
        for (int sub = 0; sub < 2; sub++)
#pragma unroll
            for (int j = 0; j < 4; j++) {
                int r = wq * 32 + sub * 16 + g * 4 + j;
                float M = m[sub][j];
#pragma unroll
                for (int gi = 1; gi < 4; gi++) M = fmaxf(M, cmB[gi][r]);
                float e0 = exp2f((m[sub][j] - M) * 1.44269504f);
                float L = ll[sub][j] * e0;
                float eg[3];
#pragma unroll
                for (int gi = 1; gi < 4; gi++) {
                    eg[gi - 1] = exp2f((cmB[gi][r] - M) * 1.44269504f);
                    L += clB[gi][r] * eg[gi - 1];
                }
                float rL = 1.0f / L;
                float* op = out + ((size_t)(b * S_ + qt * 64 + r)) * D_;
#pragma unroll
                for (int ct = 0; ct < 8; ct++) {
                    float a = o[sub][ct][j] * e0;
#pragma unroll
                    for (int gi = 1; gi < 4; gi++)
                        a += co[(size_t)(gi - 1) * (64 * 128) + (size_t)r * 128 + ct * 16 + c] * eg[gi - 1];
                    op[ct * 16 + c] = a * rL;
                }
            }
    }
}

extern "C" void kernel_launch(void* const* d_in, const int* in_sizes, int n_in,
                              void* d_out, int out_size, void* d_ws, size_t ws_size,
                              hipStream_t stream) {
    const float* x  = (const float*)d_in[0];
    const float* Wq = (const float*)d_in[1];
    const float* Wk = (const float*)d_in[2];
    const float* Wv = (const float*)d_in[3];
    float* out = (float*)d_out;   // reference output dtype is float32

    // workspace layout (bytes): q 4MB | k 4MB | vT 4MB | Wt2 768KB
    u16* q  = (u16*)d_ws;
    u16* k  = q  + (size_t)B_ * S_ * D_;
    u16* vT = k  + (size_t)B_ * S_ * D_;
    u16* Wt = vT + (size_t)B_ * S_ * D_;

    wt_kernel<<<(3 * 32 * 8 * 64) / 256, 256, 0, stream>>>(Wq, Wk, Wv, Wt);
    qkv_fused<<<(B_ * S_) / 64, 512, 0, stream>>>(x, Wt, q, k, vT);
    attn_kernel<<<(B_ * S_) / 64, 512, 0, stream>>>(q, k, vT, out);
}